// Round 15
// baseline (237.921 us; speedup 1.0000x reference)
//
#include <hip/hip_runtime.h>
#include <cstdint>
#include <cstddef>

// GraphSAGE 2-layer fused pipeline, MI355X.
// Identity: segment_mean(x[src]) @ W == segment_mean((x@W)[src]) -> GEMM before gather.
// R34 == R33 resubmitted verbatim (R33 bench failed with GPUAcquisitionTimeout;
// no counters produced, ex-bucket theory untested).
// R33 = R31 loop + EX-BUCKET layout: kill the gather's address chain.
// R32 post-mortem: epilogue-overlap null (60.3us, VGPR 44 cost occupancy);
// three VALU/cross-lane theories dead. Untouched: each stage starts with 4
// ds_bpermute (LDS pipe, ~50cy) BEFORE its loads can issue + 256B bucket row
// load + mask/firewall per node. Fix: bucketB emits pre-permuted quads
// ex[n][s][g] = {e(16s+g), e(16s+4+g), e(16s+8+g), e(16s+12+g)} -> lane (q,g)
// gets stage s's 4 row indices via ONE uint4 load (uniform across q-lanes,
// L2 broadcast). Q0 prefetched 1 node ahead; Q1 under stage-0 latency; Q2/Q3
// just-in-time (P(deg>32)~0.02%). lbkt zero-init -> stale entries are 0 ->
// firewall deleted. k_out uses a 3-op index transform. R32 preload reverted.

#define CAP 64
#define BINSZ 128        // nodes per bin (dst >> 7)
#define CH 4096          // edges per chunk block

typedef __attribute__((ext_vector_type(8))) short bf16x8v;
typedef __attribute__((ext_vector_type(4))) float f32x4v;
typedef __attribute__((ext_vector_type(2))) unsigned int u32x2v;

__device__ __forceinline__ float bf2f(unsigned short u) {
  return __uint_as_float(((unsigned int)u) << 16);
}
__device__ __forceinline__ unsigned short f2bf(float f) {
  unsigned int x = __float_as_uint(f);
  unsigned int r = (x + 0x7fffu + ((x >> 16) & 1u)) >> 16;  // RNE
  return (unsigned short)r;
}

// VALU-pipe butterfly add: y[i] = x[i] + x[i^16] / x[i^32] via permlane swaps.
__device__ __forceinline__ float swap16_add(float x) {
  u32x2v p = __builtin_amdgcn_permlane16_swap(__float_as_uint(x), __float_as_uint(x), false, false);
  return __uint_as_float(p[0]) + __uint_as_float(p[1]);
}
__device__ __forceinline__ float swap32_add(float x) {
  u32x2v p = __builtin_amdgcn_permlane32_swap(__float_as_uint(x), __float_as_uint(x), false, false);
  return __uint_as_float(p[0]) + __uint_as_float(p[1]);
}

// DPP row-rotate-add: x += rotate_row_right<N>(x), within each 16-lane row.
#define DPP_ROR_ADD(x, CTRL)                                                  \
  (x) = (x) + __int_as_float(__builtin_amdgcn_update_dpp(                     \
            __float_as_int(x), __float_as_int(x), (CTRL), 0xF, 0xF, false))

// ---------------- pass 1: per-chunk histogram over dst bins + (tail blocks) W-swizzle ----------------
__global__ __launch_bounds__(256) void k_hist(const int* __restrict__ ei,
                                              int* __restrict__ hist,
                                              const float* __restrict__ W1l,
                                              const float* __restrict__ W1r,
                                              unsigned short* __restrict__ wswz,
                                              int* __restrict__ cursor,
                                              int E, int NB, int NCH) {
  const int t = threadIdx.x;
  if (blockIdx.x >= (unsigned)NCH) {
    if (blockIdx.x == (unsigned)NCH && t == 0) *cursor = 0;  // scanA base cursor
    // wprep tail: 64 blocks cover 16384 swizzled bf16 weights
    int idx = (blockIdx.x - NCH) * 256 + t;
    int j = idx & 7;
    int lane = (idx >> 3) & 63;
    int c = (idx >> 9) & 7;
    int t4 = idx >> 12;
    int kk = t4 * 32 + (lane >> 4) * 8 + j;
    int nn = c * 16 + (lane & 15);
    float v = (nn < 64) ? W1l[kk * 64 + nn] : W1r[kk * 64 + (nn - 64)];
    wswz[idx] = f2bf(v);
    return;
  }
  __shared__ int lcnt[1024];
  const int c = blockIdx.x;
  for (int i = t; i < NB; i += 256) lcnt[i] = 0;
  __syncthreads();
  const int base = c * CH;
  const int end = min(base + CH, E);
  for (int e = base + t; e < end; e += 256) {
    int d = ei[E + e];
    atomicAdd(&lcnt[d >> 7], 1);  // LDS int atomic (native, fast)
  }
  __syncthreads();
  for (int i = t; i < NB; i += 256) hist[(size_t)i * NCH + c] = lcnt[i];
}

// ---------------- merged: [head blocks] per-bin scan over chunks  |  [tail blocks] layer-1 GEMM ----------------
__global__ __launch_bounds__(256) void k_scan_gemm(
    int* __restrict__ hist, int* __restrict__ tot, int* __restrict__ binbase,
    int* __restrict__ cursor, int NB, int NCH, int nScan,
    const float* __restrict__ x, const unsigned short* __restrict__ wswz,
    const float* __restrict__ b1, unsigned short* __restrict__ xl,
    unsigned short* __restrict__ hroot, int Nn) {
  if (blockIdx.x < (unsigned)nScan) {
    const int lane = threadIdx.x & 63;
    const int bin = blockIdx.x * 4 + (threadIdx.x >> 6);
    if (bin >= NB) return;
    int* h = hist + (size_t)bin * NCH;
    int carry = 0;
    for (int base = 0; base < NCH; base += 64) {
      int i = base + lane;
      int v = (i < NCH) ? h[i] : 0;
      int incl = v;
      #pragma unroll
      for (int d = 1; d < 64; d <<= 1) {
        int t = __shfl_up(incl, d, 64);
        if (lane >= d) incl += t;
      }
      if (i < NCH) h[i] = carry + incl - v;  // exclusive prefix within bin
      carry += __shfl(incl, 63, 64);
    }
    if (lane == 0) {
      tot[bin] = carry;
      binbase[bin] = atomicAdd(cursor, carry);  // disjoint range, order-free
    }
    return;
  }
  // ---- gemm1 body ----
  __shared__ unsigned short Bsw[16384];  // 32 KB
  const int t = threadIdx.x;
  const int bid = blockIdx.x - nScan;
  {
    const uint4* src = (const uint4*)wswz;
    uint4* dst = (uint4*)Bsw;
    #pragma unroll
    for (int i = 0; i < 8; ++i) dst[t + i * 256] = src[t + i * 256];
  }
  __syncthreads();

  const int lane = t & 63;
  const int wid = t >> 6;
  const int quad = lane >> 4;
  const int m = lane & 15;
  const int rowA = bid * 64 + wid * 16 + m;
  const float* xrow = x + (size_t)min(rowA, Nn - 1) * 128;

  f32x4v acc[8];
  #pragma unroll
  for (int c = 0; c < 8; ++c) acc[c] = (f32x4v){0.f, 0.f, 0.f, 0.f};

  #pragma unroll
  for (int t4 = 0; t4 < 4; ++t4) {
    const int koff = t4 * 32 + quad * 8;
    float4 a0 = *(const float4*)(xrow + koff);
    float4 a1 = *(const float4*)(xrow + koff + 4);
    bf16x8v af;
    af[0] = (short)f2bf(a0.x); af[1] = (short)f2bf(a0.y);
    af[2] = (short)f2bf(a0.z); af[3] = (short)f2bf(a0.w);
    af[4] = (short)f2bf(a1.x); af[5] = (short)f2bf(a1.y);
    af[6] = (short)f2bf(a1.z); af[7] = (short)f2bf(a1.w);
    #pragma unroll
    for (int c = 0; c < 8; ++c) {
      const bf16x8v bf_ = *(const bf16x8v*)&Bsw[(((t4 * 8 + c) * 64 + lane)) << 3];
      acc[c] = __builtin_amdgcn_mfma_f32_16x16x32_bf16(af, bf_, acc[c], 0, 0, 0);
    }
  }

  const int rbase = bid * 64 + wid * 16 + quad * 4;
  #pragma unroll
  for (int c = 0; c < 8; ++c) {
    const int col = c * 16 + m;
    #pragma unroll
    for (int i = 0; i < 4; ++i) {
      const int r = rbase + i;
      if (r < Nn) {
        if (c < 4) xl[(size_t)r * 64 + col] = f2bf(acc[c][i]);
        else       hroot[(size_t)r * 64 + (col - 64)] = f2bf(acc[c][i] + b1[col - 64]);
      }
    }
  }
}

// ---------------- pass 3: scatter edges to bin-sorted array (LDS cursors only) ----------------
__global__ __launch_bounds__(256) void k_scat(const int* __restrict__ ei,
                                              const int* __restrict__ hist,
                                              const int* __restrict__ binbase,
                                              unsigned int* __restrict__ part,
                                              int E, int NB, int NCH) {
  __shared__ int lcur[1024];
  const int c = blockIdx.x, t = threadIdx.x;
  for (int i = t; i < NB; i += 256)
    lcur[i] = hist[(size_t)i * NCH + c] + binbase[i];
  __syncthreads();
  const int base = c * CH;
  const int end = min(base + CH, E);
  for (int e = base + t; e < end; e += 256) {
    int s = ei[e];        // src < 2^17
    int d = ei[E + e];    // dst
    int bin = d >> 7;
    int pos = atomicAdd(&lcur[bin], 1);  // LDS int atomic; positions exact
    part[pos] = (unsigned)s | ((unsigned)(d & 127) << 17);
  }
}

// ---------------- pass 4: per-bin bucket build in LDS, EX-LAYOUT writeout ----------------
// ex[n][s][g] int4 = {lbkt[64n+16s+g], [..+4+g], [..+8+g], [..+12+g]}.
// lbkt zero-init: out-of-degree entries read as row 0 (safe, acc-masked).
__global__ __launch_bounds__(256) void k_bucketB(const int* __restrict__ binbase,
                                                 const int* __restrict__ tot,
                                                 const unsigned int* __restrict__ part,
                                                 int* __restrict__ cnt,
                                                 int* __restrict__ bucket) {
  __shared__ int lbkt[BINSZ * CAP];  // 32 KB
  __shared__ int ldeg[BINSZ];
  const int b = blockIdx.x, t = threadIdx.x;
  {
    int4* l4 = (int4*)lbkt;
    #pragma unroll 2
    for (int j = t; j < BINSZ * CAP / 4; j += 256) l4[j] = make_int4(0, 0, 0, 0);
  }
  if (t < BINSZ) ldeg[t] = 0;
  __syncthreads();
  const int e0 = binbase[b], e1 = e0 + tot[b];
  for (int i = e0 + t; i < e1; i += 256) {
    unsigned rec = part[i];
    int loc = rec >> 17;
    int p = atomicAdd(&ldeg[loc], 1);
    if (p < CAP) lbkt[loc * CAP + p] = (int)(rec & 0x1FFFFu);
  }
  __syncthreads();
  if (t < BINSZ) cnt[b * BINSZ + t] = ldeg[t];
  int4* d4 = (int4*)(bucket + (size_t)b * BINSZ * CAP);
  #pragma unroll 2
  for (int j = t; j < BINSZ * 16; j += 256) {  // 2048 int4 per bin
    int loc = j >> 4, s = (j >> 2) & 3, g = j & 3;
    int base = loc * 64 + s * 16 + g;
    d4[j] = make_int4(lbkt[base], lbkt[base + 4], lbkt[base + 8], lbkt[base + 12]);
  }
}

// ---------------- layer-1 aggregate + FUSED layer-2 GEMM, ex-bucket gather ----------------
#define LDROW(r) (*(const uint2*)(xl32 + (((unsigned)(r)) << 5) + qo))
#define ACC4(uA, uB, uC, uD)                                                     \
  a0 += (__uint_as_float(uA.x << 16) + __uint_as_float(uB.x << 16))              \
      + (__uint_as_float(uC.x << 16) + __uint_as_float(uD.x << 16));             \
  a1 += (__uint_as_float(uA.x & 0xFFFF0000u) + __uint_as_float(uB.x & 0xFFFF0000u)) \
      + (__uint_as_float(uC.x & 0xFFFF0000u) + __uint_as_float(uD.x & 0xFFFF0000u)); \
  a2 += (__uint_as_float(uA.y << 16) + __uint_as_float(uB.y << 16))              \
      + (__uint_as_float(uC.y << 16) + __uint_as_float(uD.y << 16));             \
  a3 += (__uint_as_float(uA.y & 0xFFFF0000u) + __uint_as_float(uB.y & 0xFFFF0000u)) \
      + (__uint_as_float(uC.y & 0xFFFF0000u) + __uint_as_float(uD.y & 0xFFFF0000u));
#define ACC2(uA, uB)                                                             \
  a0 += __uint_as_float(uA.x << 16) + __uint_as_float(uB.x << 16);               \
  a1 += __uint_as_float(uA.x & 0xFFFF0000u) + __uint_as_float(uB.x & 0xFFFF0000u); \
  a2 += __uint_as_float(uA.y << 16) + __uint_as_float(uB.y << 16);               \
  a3 += __uint_as_float(uA.y & 0xFFFF0000u) + __uint_as_float(uB.y & 0xFFFF0000u);
#define ACC1(u)                                                                  \
  a0 += __uint_as_float(u.x << 16);                                              \
  a1 += __uint_as_float(u.x & 0xFFFF0000u);                                      \
  a2 += __uint_as_float(u.y << 16);                                              \
  a3 += __uint_as_float(u.y & 0xFFFF0000u);
#define STAGE(Q)                                                                 \
  { uint2 uA = LDROW(Q.x), uB = LDROW(Q.y), uC = LDROW(Q.z), uD = LDROW(Q.w);    \
    ACC4(uA, uB, uC, uD); }
#define REM(Q, base)                                                             \
  { int rem = m - (base);                                                        \
    if (rem > 0) {                                                               \
      if (rem >= 8) {                                                            \
        uint2 uA = LDROW(Q.x), uB = LDROW(Q.y);                                  \
        ACC2(uA, uB);                                                            \
        if (rem > 8) {                                                           \
          uint2 u = LDROW(Q.z);                                                  \
          if ((base) + 8 + g < m) { ACC1(u); }                                   \
          if (rem > 12) {                                                        \
            uint2 u2 = LDROW(Q.w);                                               \
            if ((base) + 12 + g < m) { ACC1(u2); }                               \
          }                                                                      \
        }                                                                        \
      } else {                                                                   \
        uint2 u = LDROW(Q.x);                                                    \
        if ((base) + g < m) { ACC1(u); }                                         \
        if (rem > 4) {                                                           \
          uint2 u2 = LDROW(Q.y);                                                 \
          if ((base) + 4 + g < m) { ACC1(u2); }                                  \
        }                                                                        \
      }                                                                          \
    }                                                                            \
  }

__global__ __launch_bounds__(256) void k_agg1(
    const int* __restrict__ cnt, const int* __restrict__ bucket,
    const unsigned int* __restrict__ xl32, const unsigned int* __restrict__ hroot32,
    const float* __restrict__ W2l, const float* __restrict__ W2r,
    const float* __restrict__ b2,
    float* __restrict__ hl, float* __restrict__ hr, int Nn) {
  const int lane = threadIdx.x & 63;
  const int q = lane & 15;
  const unsigned qo = 2u * q;
  const int g = lane >> 4;
  const int nw = gridDim.x * (blockDim.x >> 6);
  int n = blockIdx.x * (blockDim.x >> 6) + (threadIdx.x >> 6);
  if (n >= Nn) return;
  const uint4* exb4 = (const uint4*)bucket;

  // one-time W2 block preload: lane (q,g) -> input cols 4q..4q+3, outputs 4g+k
  float wreg[4][4];
  float bcr[4];
  #pragma unroll
  for (int k = 0; k < 4; ++k) {
    const int o = (g << 2) + k;                 // 0..15 combined output idx
    bcr[k] = (o >= 8 && o < 15) ? b2[o - 8] : 0.f;
    #pragma unroll
    for (int j = 0; j < 4; ++j) {
      const int kk = (q << 2) + j;              // 0..63 input col
      float wv = 0.f;
      if (o < 7)                 wv = W2l[kk * 7 + o];
      else if (o >= 8 && o < 15) wv = W2r[kk * 7 + (o - 8)];
      wreg[j][k] = wv;
    }
  }

  // pipeline prologue: node n loaded (cnt, Q0, hroot); cnt of n+nw in flight
  int c  = cnt[n];
  int c1 = cnt[min(n + nw, Nn - 1)];
  int m = c < CAP ? c : CAP;
  uint4 Q0 = exb4[(((unsigned)n) << 4) + g];   // stage-0 quad
  uint2 hu = *(const uint2*)(hroot32 + ((unsigned)n << 5) + qo);

  while (true) {
    // issue NEXT node's prologue now; latency hides under this node's gather
    const int n1 = n + nw;
    const int n1c = min(n1, Nn - 1);
    const int m1 = c1 < CAP ? c1 : CAP;          // c1 loaded last iteration
    uint4 Q0N = exb4[(((unsigned)n1c) << 4) + g];
    uint2 hu1 = *(const uint2*)(hroot32 + ((unsigned)n1c << 5) + qo);
    int c2 = cnt[min(n1 + nw, Nn - 1)];

    const uint4* exq = exb4 + (((unsigned)n) << 4) + g;
    float a0 = 0.f, a1 = 0.f, a2 = 0.f, a3 = 0.f;
    if (m >= 16) {
      // stage 0 from prefetched Q0; issue Q1 under its latency
      uint2 uA = LDROW(Q0.x), uB = LDROW(Q0.y), uC = LDROW(Q0.z), uD = LDROW(Q0.w);
      uint4 Q1;
      if (m > 16) Q1 = exq[4];
      ACC4(uA, uB, uC, uD);
      if (m >= 32) {
        STAGE(Q1);
        if (m >= 48) {
          uint4 Q2 = exq[8];
          STAGE(Q2);
          if (m >= 64) { uint4 Q3 = exq[12]; STAGE(Q3); }
          else if (m > 48) { uint4 Q3 = exq[12]; REM(Q3, 48); }
        } else if (m > 32) {
          uint4 Q2 = exq[8];
          REM(Q2, 32);
        }
      } else if (m > 16) {
        REM(Q1, 16);
      }
    } else {
      REM(Q0, 0);
    }

    // merge the 4 edge-subgroups: VALU-pipe permlane butterfly
    a0 = swap32_add(swap16_add(a0));
    a1 = swap32_add(swap16_add(a1));
    a2 = swap32_add(swap16_add(a2));
    a3 = swap32_add(swap16_add(a3));

    // fused epilogue: h = relu(mean + hroot), then layer-2 partial dot
    {
      float inv = __builtin_amdgcn_rcpf(c > 0 ? (float)c : 1.f);
      float h0 = fmaxf(fmaf(a0, inv, __uint_as_float(hu.x << 16)), 0.f);
      float h1 = fmaxf(fmaf(a1, inv, __uint_as_float(hu.x & 0xFFFF0000u)), 0.f);
      float h2 = fmaxf(fmaf(a2, inv, __uint_as_float(hu.y << 16)), 0.f);
      float h3 = fmaxf(fmaf(a3, inv, __uint_as_float(hu.y & 0xFFFF0000u)), 0.f);
      float r0 = h0 * wreg[0][0];
      r0 = fmaf(h1, wreg[1][0], r0); r0 = fmaf(h2, wreg[2][0], r0); r0 = fmaf(h3, wreg[3][0], r0);
      float r1 = h0 * wreg[0][1];
      r1 = fmaf(h1, wreg[1][1], r1); r1 = fmaf(h2, wreg[2][1], r1); r1 = fmaf(h3, wreg[3][1], r1);
      float r2 = h0 * wreg[0][2];
      r2 = fmaf(h1, wreg[1][2], r2); r2 = fmaf(h2, wreg[2][2], r2); r2 = fmaf(h3, wreg[3][2], r2);
      float r3 = h0 * wreg[0][3];
      r3 = fmaf(h1, wreg[1][3], r3); r3 = fmaf(h2, wreg[2][3], r3); r3 = fmaf(h3, wreg[3][3], r3);
      // 16-lane row reduce via DPP row_ror rotation-adds (VALU pipe).
      DPP_ROR_ADD(r0, 0x128); DPP_ROR_ADD(r1, 0x128);
      DPP_ROR_ADD(r2, 0x128); DPP_ROR_ADD(r3, 0x128);
      DPP_ROR_ADD(r0, 0x124); DPP_ROR_ADD(r1, 0x124);
      DPP_ROR_ADD(r2, 0x124); DPP_ROR_ADD(r3, 0x124);
      DPP_ROR_ADD(r0, 0x122); DPP_ROR_ADD(r1, 0x122);
      DPP_ROR_ADD(r2, 0x122); DPP_ROR_ADD(r3, 0x122);
      DPP_ROR_ADD(r0, 0x121); DPP_ROR_ADD(r1, 0x121);
      DPP_ROR_ADD(r2, 0x121); DPP_ROR_ADD(r3, 0x121);
      r0 += bcr[0]; r1 += bcr[1]; r2 += bcr[2]; r3 += bcr[3];
      if (q < 4) {
        float v = r0;
        if (q == 1) v = r1;
        else if (q == 2) v = r2;
        else if (q == 3) v = r3;
        float* bp = (g < 2) ? hl : hr;
        bp[((unsigned)n << 3) + ((g & 1) << 2) + q] = v;
      }
    }
    if (n1 >= Nn) break;
    // rotate pipeline
    n = n1; c = c1; c1 = c2; m = m1;
    Q0 = Q0N; hu = hu1;
  }
}

// ---------------- layer-2 aggregate + log_softmax; 8 nodes/wave, 8 lanes/node ----------------
__global__ __launch_bounds__(256) void k_out(
    const int* __restrict__ cnt, const int* __restrict__ bucket,
    const float* __restrict__ hl, const float* __restrict__ hr,
    float* __restrict__ out, int Nn) {
  const int lane = threadIdx.x & 63;
  const int c = lane & 7;
  const int sub = lane >> 3;
  const int gw = blockIdx.x * (blockDim.x >> 6) + (threadIdx.x >> 6);
  const int n = gw * 8 + sub;
  if (n >= Nn) return;
  int cn = cnt[n];
  int m = cn < CAP ? cn : CAP;
  const bool act = (c < 7);
  float acc = 0.f;
  for (int e0 = 0; e0 < m; e0 += 8) {
    int e = e0 + c;
    // ex-layout inverse: edge e lives at int offset (e&~15) + ((e&3)<<2) + ((e>>2)&3)
    int exi = (e & ~15) | ((e & 3) << 2) | ((e >> 2) & 3);
    int bv = (e < m) ? bucket[(size_t)n * CAP + exi] : 0;
    #pragma unroll
    for (int cc = 0; cc < 8; ++cc) {
      if (e0 + cc < m) {
        int s = __shfl(bv, (lane & 56) + cc, 64);
        if ((unsigned)s >= (unsigned)Nn) s = 0;
        if (act) acc += hl[(size_t)s * 8 + c];
      }
    }
  }
  float dd = cn > 0 ? (float)cn : 1.f;
  float v = act ? (acc / dd + hr[(size_t)n * 8 + c]) : -INFINITY;
  float mx = v;
  mx = fmaxf(mx, __shfl_xor(mx, 1, 8));
  mx = fmaxf(mx, __shfl_xor(mx, 2, 8));
  mx = fmaxf(mx, __shfl_xor(mx, 4, 8));
  float ex = act ? expf(v - mx) : 0.f;
  float s2 = ex;
  s2 += __shfl_xor(s2, 1, 8);
  s2 += __shfl_xor(s2, 2, 8);
  s2 += __shfl_xor(s2, 4, 8);
  float res = v - mx - logf(s2);
  if (act) out[(size_t)n * 7 + c] = res;
}

static inline size_t alignup(size_t v) { return (v + 255) & ~(size_t)255; }

extern "C" void kernel_launch(void* const* d_in, const int* in_sizes, int n_in,
                              void* d_out, int out_size, void* d_ws, size_t ws_size,
                              hipStream_t stream) {
  const int N = in_sizes[0] / 128;
  const int E = in_sizes[1] / 2;
  const int NB = (N + BINSZ - 1) / BINSZ;   // 782 bins
  const int Np = NB * BINSZ;                // padded node count
  const int NCH = (E + CH - 1) / CH;        // 391 chunks
  const int nScan = (NB + 3) / 4;           // scanA head blocks

  const float* x   = (const float*)d_in[0];
  const int*   ei  = (const int*)d_in[1];
  const float* W1l = (const float*)d_in[2];
  const float* W1r = (const float*)d_in[3];
  const float* b1  = (const float*)d_in[4];
  const float* W2l = (const float*)d_in[5];
  const float* W2r = (const float*)d_in[6];
  const float* b2  = (const float*)d_in[7];
  float* out = (float*)d_out;

  // workspace carve (~70 MB)
  char* p = (char*)d_ws;
  int* hist    = (int*)p;            p += alignup((size_t)NB * NCH * 4);
  int* tot     = (int*)p;            p += alignup((size_t)NB * 4);
  int* binbase = (int*)p;            p += alignup((size_t)(NB + 1) * 4);
  int* cursor  = (int*)p;            p += alignup(4);
  unsigned int* part = (unsigned int*)p; p += alignup((size_t)E * 4);
  int* cnt    = (int*)p;             p += alignup((size_t)Np * 4);
  int* bucket = (int*)p;             p += alignup((size_t)Np * CAP * 4);
  unsigned short* wswz = (unsigned short*)p; p += alignup((size_t)16384 * 2);
  unsigned short* xl    = (unsigned short*)p; p += alignup((size_t)N * 64 * 2);
  unsigned short* hroot = (unsigned short*)p; p += alignup((size_t)N * 64 * 2);
  float* hl  = (float*)p;            p += alignup((size_t)N * 8 * 4);
  float* hr  = (float*)p;            p += alignup((size_t)N * 8 * 4);

  dim3 b256(256);
  // hist blocks [0,NCH) + wprep/cursor tail blocks [NCH, NCH+64)
  k_hist<<<dim3(NCH + 64), b256, 0, stream>>>(ei, hist, W1l, W1r, wswz, cursor, E, NB, NCH);
  // scanA head blocks [0,nScan) + gemm1 tail blocks
  k_scan_gemm<<<dim3(nScan + (N + 63) / 64), b256, 0, stream>>>(
      hist, tot, binbase, cursor, NB, NCH, nScan, x, wswz, b1, xl, hroot, N);
  k_scat<<<dim3(NCH), b256, 0, stream>>>(ei, hist, binbase, part, E, NB, NCH);
  k_bucketB<<<dim3(NB), b256, 0, stream>>>(binbase, tot, part, cnt, bucket);
  k_agg1<<<dim3(2048), b256, 0, stream>>>(cnt, bucket,
      (const unsigned int*)xl, (const unsigned int*)hroot,
      W2l, W2r, b2, hl, hr, N);
  const int waves_out = (N + 7) / 8;
  k_out<<<dim3((waves_out + 3) / 4), b256, 0, stream>>>(cnt, bucket, hl, hr, out, N);
}

// Round 16
// 236.348 us; speedup vs baseline: 1.0067x; 1.0067x over previous
//
#include <hip/hip_runtime.h>
#include <cstdint>
#include <cstddef>

// GraphSAGE 2-layer fused pipeline, MI355X.
// Identity: segment_mean(x[src]) @ W == segment_mean((x@W)[src]) -> GEMM before gather.
// R35 = R34 (ex-bucket, verified -6.8us: agg1 60.3->53.5) + packed-f32
// accumulation: gather unpack+acc restructured as f32x2v ({col-lo,col-hi} of
// each uint) so clang emits v_pk_add_f32 -> 16 adds/stage become 8 pk_adds
// (32->24 VALU/stage, -25% gather VALU; agg1 VALU-busy ~30us is the bottleneck
// at 56% busy / 22% HBM). Same FP order per column. All else identical to R34.
// Stopping rule: agg1 >= 52us => at L3-gather latency floor; revert+plateau.

#define CAP 64
#define BINSZ 128        // nodes per bin (dst >> 7)
#define CH 4096          // edges per chunk block

typedef __attribute__((ext_vector_type(8))) short bf16x8v;
typedef __attribute__((ext_vector_type(4))) float f32x4v;
typedef __attribute__((ext_vector_type(2))) float f32x2v;
typedef __attribute__((ext_vector_type(2))) unsigned int u32x2v;

__device__ __forceinline__ float bf2f(unsigned short u) {
  return __uint_as_float(((unsigned int)u) << 16);
}
__device__ __forceinline__ unsigned short f2bf(float f) {
  unsigned int x = __float_as_uint(f);
  unsigned int r = (x + 0x7fffu + ((x >> 16) & 1u)) >> 16;  // RNE
  return (unsigned short)r;
}

// unpack one uint (2 packed bf16 cols) -> f32x2v {lo, hi}
__device__ __forceinline__ f32x2v bfpair(unsigned u) {
  f32x2v r;
  r.x = __uint_as_float(u << 16);
  r.y = __uint_as_float(u & 0xFFFF0000u);
  return r;
}

// VALU-pipe butterfly add: y[i] = x[i] + x[i^16] / x[i^32] via permlane swaps.
__device__ __forceinline__ float swap16_add(float x) {
  u32x2v p = __builtin_amdgcn_permlane16_swap(__float_as_uint(x), __float_as_uint(x), false, false);
  return __uint_as_float(p[0]) + __uint_as_float(p[1]);
}
__device__ __forceinline__ float swap32_add(float x) {
  u32x2v p = __builtin_amdgcn_permlane32_swap(__float_as_uint(x), __float_as_uint(x), false, false);
  return __uint_as_float(p[0]) + __uint_as_float(p[1]);
}

// DPP row-rotate-add: x += rotate_row_right<N>(x), within each 16-lane row.
#define DPP_ROR_ADD(x, CTRL)                                                  \
  (x) = (x) + __int_as_float(__builtin_amdgcn_update_dpp(                     \
            __float_as_int(x), __float_as_int(x), (CTRL), 0xF, 0xF, false))

// ---------------- pass 1: per-chunk histogram over dst bins + (tail blocks) W-swizzle ----------------
__global__ __launch_bounds__(256) void k_hist(const int* __restrict__ ei,
                                              int* __restrict__ hist,
                                              const float* __restrict__ W1l,
                                              const float* __restrict__ W1r,
                                              unsigned short* __restrict__ wswz,
                                              int* __restrict__ cursor,
                                              int E, int NB, int NCH) {
  const int t = threadIdx.x;
  if (blockIdx.x >= (unsigned)NCH) {
    if (blockIdx.x == (unsigned)NCH && t == 0) *cursor = 0;  // scanA base cursor
    // wprep tail: 64 blocks cover 16384 swizzled bf16 weights
    int idx = (blockIdx.x - NCH) * 256 + t;
    int j = idx & 7;
    int lane = (idx >> 3) & 63;
    int c = (idx >> 9) & 7;
    int t4 = idx >> 12;
    int kk = t4 * 32 + (lane >> 4) * 8 + j;
    int nn = c * 16 + (lane & 15);
    float v = (nn < 64) ? W1l[kk * 64 + nn] : W1r[kk * 64 + (nn - 64)];
    wswz[idx] = f2bf(v);
    return;
  }
  __shared__ int lcnt[1024];
  const int c = blockIdx.x;
  for (int i = t; i < NB; i += 256) lcnt[i] = 0;
  __syncthreads();
  const int base = c * CH;
  const int end = min(base + CH, E);
  for (int e = base + t; e < end; e += 256) {
    int d = ei[E + e];
    atomicAdd(&lcnt[d >> 7], 1);  // LDS int atomic (native, fast)
  }
  __syncthreads();
  for (int i = t; i < NB; i += 256) hist[(size_t)i * NCH + c] = lcnt[i];
}

// ---------------- merged: [head blocks] per-bin scan over chunks  |  [tail blocks] layer-1 GEMM ----------------
__global__ __launch_bounds__(256) void k_scan_gemm(
    int* __restrict__ hist, int* __restrict__ tot, int* __restrict__ binbase,
    int* __restrict__ cursor, int NB, int NCH, int nScan,
    const float* __restrict__ x, const unsigned short* __restrict__ wswz,
    const float* __restrict__ b1, unsigned short* __restrict__ xl,
    unsigned short* __restrict__ hroot, int Nn) {
  if (blockIdx.x < (unsigned)nScan) {
    const int lane = threadIdx.x & 63;
    const int bin = blockIdx.x * 4 + (threadIdx.x >> 6);
    if (bin >= NB) return;
    int* h = hist + (size_t)bin * NCH;
    int carry = 0;
    for (int base = 0; base < NCH; base += 64) {
      int i = base + lane;
      int v = (i < NCH) ? h[i] : 0;
      int incl = v;
      #pragma unroll
      for (int d = 1; d < 64; d <<= 1) {
        int t = __shfl_up(incl, d, 64);
        if (lane >= d) incl += t;
      }
      if (i < NCH) h[i] = carry + incl - v;  // exclusive prefix within bin
      carry += __shfl(incl, 63, 64);
    }
    if (lane == 0) {
      tot[bin] = carry;
      binbase[bin] = atomicAdd(cursor, carry);  // disjoint range, order-free
    }
    return;
  }
  // ---- gemm1 body ----
  __shared__ unsigned short Bsw[16384];  // 32 KB
  const int t = threadIdx.x;
  const int bid = blockIdx.x - nScan;
  {
    const uint4* src = (const uint4*)wswz;
    uint4* dst = (uint4*)Bsw;
    #pragma unroll
    for (int i = 0; i < 8; ++i) dst[t + i * 256] = src[t + i * 256];
  }
  __syncthreads();

  const int lane = t & 63;
  const int wid = t >> 6;
  const int quad = lane >> 4;
  const int m = lane & 15;
  const int rowA = bid * 64 + wid * 16 + m;
  const float* xrow = x + (size_t)min(rowA, Nn - 1) * 128;

  f32x4v acc[8];
  #pragma unroll
  for (int c = 0; c < 8; ++c) acc[c] = (f32x4v){0.f, 0.f, 0.f, 0.f};

  #pragma unroll
  for (int t4 = 0; t4 < 4; ++t4) {
    const int koff = t4 * 32 + quad * 8;
    float4 a0 = *(const float4*)(xrow + koff);
    float4 a1 = *(const float4*)(xrow + koff + 4);
    bf16x8v af;
    af[0] = (short)f2bf(a0.x); af[1] = (short)f2bf(a0.y);
    af[2] = (short)f2bf(a0.z); af[3] = (short)f2bf(a0.w);
    af[4] = (short)f2bf(a1.x); af[5] = (short)f2bf(a1.y);
    af[6] = (short)f2bf(a1.z); af[7] = (short)f2bf(a1.w);
    #pragma unroll
    for (int c = 0; c < 8; ++c) {
      const bf16x8v bf_ = *(const bf16x8v*)&Bsw[(((t4 * 8 + c) * 64 + lane)) << 3];
      acc[c] = __builtin_amdgcn_mfma_f32_16x16x32_bf16(af, bf_, acc[c], 0, 0, 0);
    }
  }

  const int rbase = bid * 64 + wid * 16 + quad * 4;
  #pragma unroll
  for (int c = 0; c < 8; ++c) {
    const int col = c * 16 + m;
    #pragma unroll
    for (int i = 0; i < 4; ++i) {
      const int r = rbase + i;
      if (r < Nn) {
        if (c < 4) xl[(size_t)r * 64 + col] = f2bf(acc[c][i]);
        else       hroot[(size_t)r * 64 + (col - 64)] = f2bf(acc[c][i] + b1[col - 64]);
      }
    }
  }
}

// ---------------- pass 3: scatter edges to bin-sorted array (LDS cursors only) ----------------
__global__ __launch_bounds__(256) void k_scat(const int* __restrict__ ei,
                                              const int* __restrict__ hist,
                                              const int* __restrict__ binbase,
                                              unsigned int* __restrict__ part,
                                              int E, int NB, int NCH) {
  __shared__ int lcur[1024];
  const int c = blockIdx.x, t = threadIdx.x;
  for (int i = t; i < NB; i += 256)
    lcur[i] = hist[(size_t)i * NCH + c] + binbase[i];
  __syncthreads();
  const int base = c * CH;
  const int end = min(base + CH, E);
  for (int e = base + t; e < end; e += 256) {
    int s = ei[e];        // src < 2^17
    int d = ei[E + e];    // dst
    int bin = d >> 7;
    int pos = atomicAdd(&lcur[bin], 1);  // LDS int atomic; positions exact
    part[pos] = (unsigned)s | ((unsigned)(d & 127) << 17);
  }
}

// ---------------- pass 4: per-bin bucket build in LDS, EX-LAYOUT writeout ----------------
// ex[n][s][g] int4 = {lbkt[64n+16s+g], [..+4+g], [..+8+g], [..+12+g]}.
// lbkt zero-init: out-of-degree entries read as row 0 (safe, acc-masked).
__global__ __launch_bounds__(256) void k_bucketB(const int* __restrict__ binbase,
                                                 const int* __restrict__ tot,
                                                 const unsigned int* __restrict__ part,
                                                 int* __restrict__ cnt,
                                                 int* __restrict__ bucket) {
  __shared__ int lbkt[BINSZ * CAP];  // 32 KB
  __shared__ int ldeg[BINSZ];
  const int b = blockIdx.x, t = threadIdx.x;
  {
    int4* l4 = (int4*)lbkt;
    #pragma unroll 2
    for (int j = t; j < BINSZ * CAP / 4; j += 256) l4[j] = make_int4(0, 0, 0, 0);
  }
  if (t < BINSZ) ldeg[t] = 0;
  __syncthreads();
  const int e0 = binbase[b], e1 = e0 + tot[b];
  for (int i = e0 + t; i < e1; i += 256) {
    unsigned rec = part[i];
    int loc = rec >> 17;
    int p = atomicAdd(&ldeg[loc], 1);
    if (p < CAP) lbkt[loc * CAP + p] = (int)(rec & 0x1FFFFu);
  }
  __syncthreads();
  if (t < BINSZ) cnt[b * BINSZ + t] = ldeg[t];
  int4* d4 = (int4*)(bucket + (size_t)b * BINSZ * CAP);
  #pragma unroll 2
  for (int j = t; j < BINSZ * 16; j += 256) {  // 2048 int4 per bin
    int loc = j >> 4, s = (j >> 2) & 3, g = j & 3;
    int base = loc * 64 + s * 16 + g;
    d4[j] = make_int4(lbkt[base], lbkt[base + 4], lbkt[base + 8], lbkt[base + 12]);
  }
}

// ---------------- layer-1 aggregate + FUSED layer-2 GEMM, ex-bucket gather ----------------
#define LDROW(r) (*(const uint2*)(xl32 + (((unsigned)(r)) << 5) + qo))
#define ACC4(uA, uB, uC, uD)                                                     \
  A01 += (bfpair(uA.x) + bfpair(uB.x)) + (bfpair(uC.x) + bfpair(uD.x));          \
  A23 += (bfpair(uA.y) + bfpair(uB.y)) + (bfpair(uC.y) + bfpair(uD.y));
#define ACC2(uA, uB)                                                             \
  A01 += bfpair(uA.x) + bfpair(uB.x);                                            \
  A23 += bfpair(uA.y) + bfpair(uB.y);
#define ACC1(u)                                                                  \
  A01 += bfpair(u.x);                                                            \
  A23 += bfpair(u.y);
#define STAGE(Q)                                                                 \
  { uint2 uA = LDROW(Q.x), uB = LDROW(Q.y), uC = LDROW(Q.z), uD = LDROW(Q.w);    \
    ACC4(uA, uB, uC, uD); }
#define REM(Q, base)                                                             \
  { int rem = m - (base);                                                        \
    if (rem > 0) {                                                               \
      if (rem >= 8) {                                                            \
        uint2 uA = LDROW(Q.x), uB = LDROW(Q.y);                                  \
        ACC2(uA, uB);                                                            \
        if (rem > 8) {                                                           \
          uint2 u = LDROW(Q.z);                                                  \
          if ((base) + 8 + g < m) { ACC1(u); }                                   \
          if (rem > 12) {                                                        \
            uint2 u2 = LDROW(Q.w);                                               \
            if ((base) + 12 + g < m) { ACC1(u2); }                               \
          }                                                                      \
        }                                                                        \
      } else {                                                                   \
        uint2 u = LDROW(Q.x);                                                    \
        if ((base) + g < m) { ACC1(u); }                                         \
        if (rem > 4) {                                                           \
          uint2 u2 = LDROW(Q.y);                                                 \
          if ((base) + 4 + g < m) { ACC1(u2); }                                  \
        }                                                                        \
      }                                                                          \
    }                                                                            \
  }

__global__ __launch_bounds__(256) void k_agg1(
    const int* __restrict__ cnt, const int* __restrict__ bucket,
    const unsigned int* __restrict__ xl32, const unsigned int* __restrict__ hroot32,
    const float* __restrict__ W2l, const float* __restrict__ W2r,
    const float* __restrict__ b2,
    float* __restrict__ hl, float* __restrict__ hr, int Nn) {
  const int lane = threadIdx.x & 63;
  const int q = lane & 15;
  const unsigned qo = 2u * q;
  const int g = lane >> 4;
  const int nw = gridDim.x * (blockDim.x >> 6);
  int n = blockIdx.x * (blockDim.x >> 6) + (threadIdx.x >> 6);
  if (n >= Nn) return;
  const uint4* exb4 = (const uint4*)bucket;

  // one-time W2 block preload: lane (q,g) -> input cols 4q..4q+3, outputs 4g+k
  float wreg[4][4];
  float bcr[4];
  #pragma unroll
  for (int k = 0; k < 4; ++k) {
    const int o = (g << 2) + k;                 // 0..15 combined output idx
    bcr[k] = (o >= 8 && o < 15) ? b2[o - 8] : 0.f;
    #pragma unroll
    for (int j = 0; j < 4; ++j) {
      const int kk = (q << 2) + j;              // 0..63 input col
      float wv = 0.f;
      if (o < 7)                 wv = W2l[kk * 7 + o];
      else if (o >= 8 && o < 15) wv = W2r[kk * 7 + (o - 8)];
      wreg[j][k] = wv;
    }
  }

  // pipeline prologue: node n loaded (cnt, Q0, hroot); cnt of n+nw in flight
  int c  = cnt[n];
  int c1 = cnt[min(n + nw, Nn - 1)];
  int m = c < CAP ? c : CAP;
  uint4 Q0 = exb4[(((unsigned)n) << 4) + g];   // stage-0 quad
  uint2 hu = *(const uint2*)(hroot32 + ((unsigned)n << 5) + qo);

  while (true) {
    // issue NEXT node's prologue now; latency hides under this node's gather
    const int n1 = n + nw;
    const int n1c = min(n1, Nn - 1);
    const int m1 = c1 < CAP ? c1 : CAP;          // c1 loaded last iteration
    uint4 Q0N = exb4[(((unsigned)n1c) << 4) + g];
    uint2 hu1 = *(const uint2*)(hroot32 + ((unsigned)n1c << 5) + qo);
    int c2 = cnt[min(n1 + nw, Nn - 1)];

    const uint4* exq = exb4 + (((unsigned)n) << 4) + g;
    f32x2v A01 = (f32x2v){0.f, 0.f};
    f32x2v A23 = (f32x2v){0.f, 0.f};
    if (m >= 16) {
      // stage 0 from prefetched Q0; issue Q1 under its latency
      uint2 uA = LDROW(Q0.x), uB = LDROW(Q0.y), uC = LDROW(Q0.z), uD = LDROW(Q0.w);
      uint4 Q1;
      if (m > 16) Q1 = exq[4];
      ACC4(uA, uB, uC, uD);
      if (m >= 32) {
        STAGE(Q1);
        if (m >= 48) {
          uint4 Q2 = exq[8];
          STAGE(Q2);
          if (m >= 64) { uint4 Q3 = exq[12]; STAGE(Q3); }
          else if (m > 48) { uint4 Q3 = exq[12]; REM(Q3, 48); }
        } else if (m > 32) {
          uint4 Q2 = exq[8];
          REM(Q2, 32);
        }
      } else if (m > 16) {
        REM(Q1, 16);
      }
    } else {
      REM(Q0, 0);
    }

    // merge the 4 edge-subgroups: VALU-pipe permlane butterfly
    float a0 = swap32_add(swap16_add(A01.x));
    float a1 = swap32_add(swap16_add(A01.y));
    float a2 = swap32_add(swap16_add(A23.x));
    float a3 = swap32_add(swap16_add(A23.y));

    // fused epilogue: h = relu(mean + hroot), then layer-2 partial dot
    {
      float inv = __builtin_amdgcn_rcpf(c > 0 ? (float)c : 1.f);
      float h0 = fmaxf(fmaf(a0, inv, __uint_as_float(hu.x << 16)), 0.f);
      float h1 = fmaxf(fmaf(a1, inv, __uint_as_float(hu.x & 0xFFFF0000u)), 0.f);
      float h2 = fmaxf(fmaf(a2, inv, __uint_as_float(hu.y << 16)), 0.f);
      float h3 = fmaxf(fmaf(a3, inv, __uint_as_float(hu.y & 0xFFFF0000u)), 0.f);
      float r0 = h0 * wreg[0][0];
      r0 = fmaf(h1, wreg[1][0], r0); r0 = fmaf(h2, wreg[2][0], r0); r0 = fmaf(h3, wreg[3][0], r0);
      float r1 = h0 * wreg[0][1];
      r1 = fmaf(h1, wreg[1][1], r1); r1 = fmaf(h2, wreg[2][1], r1); r1 = fmaf(h3, wreg[3][1], r1);
      float r2 = h0 * wreg[0][2];
      r2 = fmaf(h1, wreg[1][2], r2); r2 = fmaf(h2, wreg[2][2], r2); r2 = fmaf(h3, wreg[3][2], r2);
      float r3 = h0 * wreg[0][3];
      r3 = fmaf(h1, wreg[1][3], r3); r3 = fmaf(h2, wreg[2][3], r3); r3 = fmaf(h3, wreg[3][3], r3);
      // 16-lane row reduce via DPP row_ror rotation-adds (VALU pipe).
      DPP_ROR_ADD(r0, 0x128); DPP_ROR_ADD(r1, 0x128);
      DPP_ROR_ADD(r2, 0x128); DPP_ROR_ADD(r3, 0x128);
      DPP_ROR_ADD(r0, 0x124); DPP_ROR_ADD(r1, 0x124);
      DPP_ROR_ADD(r2, 0x124); DPP_ROR_ADD(r3, 0x124);
      DPP_ROR_ADD(r0, 0x122); DPP_ROR_ADD(r1, 0x122);
      DPP_ROR_ADD(r2, 0x122); DPP_ROR_ADD(r3, 0x122);
      DPP_ROR_ADD(r0, 0x121); DPP_ROR_ADD(r1, 0x121);
      DPP_ROR_ADD(r2, 0x121); DPP_ROR_ADD(r3, 0x121);
      r0 += bcr[0]; r1 += bcr[1]; r2 += bcr[2]; r3 += bcr[3];
      if (q < 4) {
        float v = r0;
        if (q == 1) v = r1;
        else if (q == 2) v = r2;
        else if (q == 3) v = r3;
        float* bp = (g < 2) ? hl : hr;
        bp[((unsigned)n << 3) + ((g & 1) << 2) + q] = v;
      }
    }
    if (n1 >= Nn) break;
    // rotate pipeline
    n = n1; c = c1; c1 = c2; m = m1;
    Q0 = Q0N; hu = hu1;
  }
}

// ---------------- layer-2 aggregate + log_softmax; 8 nodes/wave, 8 lanes/node ----------------
__global__ __launch_bounds__(256) void k_out(
    const int* __restrict__ cnt, const int* __restrict__ bucket,
    const float* __restrict__ hl, const float* __restrict__ hr,
    float* __restrict__ out, int Nn) {
  const int lane = threadIdx.x & 63;
  const int c = lane & 7;
  const int sub = lane >> 3;
  const int gw = blockIdx.x * (blockDim.x >> 6) + (threadIdx.x >> 6);
  const int n = gw * 8 + sub;
  if (n >= Nn) return;
  int cn = cnt[n];
  int m = cn < CAP ? cn : CAP;
  const bool act = (c < 7);
  float acc = 0.f;
  for (int e0 = 0; e0 < m; e0 += 8) {
    int e = e0 + c;
    // ex-layout inverse: edge e lives at int offset (e&~15) + ((e&3)<<2) + ((e>>2)&3)
    int exi = (e & ~15) | ((e & 3) << 2) | ((e >> 2) & 3);
    int bv = (e < m) ? bucket[(size_t)n * CAP + exi] : 0;
    #pragma unroll
    for (int cc = 0; cc < 8; ++cc) {
      if (e0 + cc < m) {
        int s = __shfl(bv, (lane & 56) + cc, 64);
        if ((unsigned)s >= (unsigned)Nn) s = 0;
        if (act) acc += hl[(size_t)s * 8 + c];
      }
    }
  }
  float dd = cn > 0 ? (float)cn : 1.f;
  float v = act ? (acc / dd + hr[(size_t)n * 8 + c]) : -INFINITY;
  float mx = v;
  mx = fmaxf(mx, __shfl_xor(mx, 1, 8));
  mx = fmaxf(mx, __shfl_xor(mx, 2, 8));
  mx = fmaxf(mx, __shfl_xor(mx, 4, 8));
  float ex = act ? expf(v - mx) : 0.f;
  float s2 = ex;
  s2 += __shfl_xor(s2, 1, 8);
  s2 += __shfl_xor(s2, 2, 8);
  s2 += __shfl_xor(s2, 4, 8);
  float res = v - mx - logf(s2);
  if (act) out[(size_t)n * 7 + c] = res;
}

static inline size_t alignup(size_t v) { return (v + 255) & ~(size_t)255; }

extern "C" void kernel_launch(void* const* d_in, const int* in_sizes, int n_in,
                              void* d_out, int out_size, void* d_ws, size_t ws_size,
                              hipStream_t stream) {
  const int N = in_sizes[0] / 128;
  const int E = in_sizes[1] / 2;
  const int NB = (N + BINSZ - 1) / BINSZ;   // 782 bins
  const int Np = NB * BINSZ;                // padded node count
  const int NCH = (E + CH - 1) / CH;        // 391 chunks
  const int nScan = (NB + 3) / 4;           // scanA head blocks

  const float* x   = (const float*)d_in[0];
  const int*   ei  = (const int*)d_in[1];
  const float* W1l = (const float*)d_in[2];
  const float* W1r = (const float*)d_in[3];
  const float* b1  = (const float*)d_in[4];
  const float* W2l = (const float*)d_in[5];
  const float* W2r = (const float*)d_in[6];
  const float* b2  = (const float*)d_in[7];
  float* out = (float*)d_out;

  // workspace carve (~70 MB)
  char* p = (char*)d_ws;
  int* hist    = (int*)p;            p += alignup((size_t)NB * NCH * 4);
  int* tot     = (int*)p;            p += alignup((size_t)NB * 4);
  int* binbase = (int*)p;            p += alignup((size_t)(NB + 1) * 4);
  int* cursor  = (int*)p;            p += alignup(4);
  unsigned int* part = (unsigned int*)p; p += alignup((size_t)E * 4);
  int* cnt    = (int*)p;             p += alignup((size_t)Np * 4);
  int* bucket = (int*)p;             p += alignup((size_t)Np * CAP * 4);
  unsigned short* wswz = (unsigned short*)p; p += alignup((size_t)16384 * 2);
  unsigned short* xl    = (unsigned short*)p; p += alignup((size_t)N * 64 * 2);
  unsigned short* hroot = (unsigned short*)p; p += alignup((size_t)N * 64 * 2);
  float* hl  = (float*)p;            p += alignup((size_t)N * 8 * 4);
  float* hr  = (float*)p;            p += alignup((size_t)N * 8 * 4);

  dim3 b256(256);
  // hist blocks [0,NCH) + wprep/cursor tail blocks [NCH, NCH+64)
  k_hist<<<dim3(NCH + 64), b256, 0, stream>>>(ei, hist, W1l, W1r, wswz, cursor, E, NB, NCH);
  // scanA head blocks [0,nScan) + gemm1 tail blocks
  k_scan_gemm<<<dim3(nScan + (N + 63) / 64), b256, 0, stream>>>(
      hist, tot, binbase, cursor, NB, NCH, nScan, x, wswz, b1, xl, hroot, N);
  k_scat<<<dim3(NCH), b256, 0, stream>>>(ei, hist, binbase, part, E, NB, NCH);
  k_bucketB<<<dim3(NB), b256, 0, stream>>>(binbase, tot, part, cnt, bucket);
  k_agg1<<<dim3(2048), b256, 0, stream>>>(cnt, bucket,
      (const unsigned int*)xl, (const unsigned int*)hroot,
      W2l, W2r, b2, hl, hr, N);
  const int waves_out = (N + 7) / 8;
  k_out<<<dim3((waves_out + 3) / 4), b256, 0, stream>>>(cnt, bucket, hl, hr, out, N);
}